// Round 3
// baseline (7827.066 us; speedup 1.0000x reference)
//
#include <hip/hip_runtime.h>
#include <stdint.h>

// ---------- types / helpers ----------
typedef short bf16x8 __attribute__((ext_vector_type(8)));   // 8 bf16 = 4 VGPR (MFMA A/B frag)
typedef float f32x4  __attribute__((ext_vector_type(4)));   // MFMA C/D frag

__device__ __forceinline__ unsigned short f2bf(float x) {
  unsigned int u = __builtin_bit_cast(unsigned int, x);
  u += 0x7fffu + ((u >> 16) & 1u);
  return (unsigned short)(u >> 16);
}
__device__ __forceinline__ float bf2f(unsigned short b) {
  unsigned int u = ((unsigned int)b) << 16;
  return __builtin_bit_cast(float, u);
}
__device__ __forceinline__ f32x4 mfma16(bf16x8 a, bf16x8 b, f32x4 c) {
  return __builtin_amdgcn_mfma_f32_16x16x32_bf16(a, b, c, 0, 0, 0);
}
// load 8 consecutive f32, split into hi/lo bf16 (hi+lo ~ f32-exact)
__device__ __forceinline__ void split8(const float* __restrict__ p, bf16x8* h, bf16x8* l) {
  float4 a = *reinterpret_cast<const float4*>(p);
  float4 b = *reinterpret_cast<const float4*>(p + 4);
  float v[8] = {a.x, a.y, a.z, a.w, b.x, b.y, b.z, b.w};
  bf16x8 hh, ll;
#pragma unroll
  for (int i = 0; i < 8; ++i) {
    unsigned short hb = f2bf(v[i]);
    hh[i] = (short)hb;
    ll[i] = (short)f2bf(v[i] - bf2f(hb));
  }
  *h = hh; *l = ll;
}
__device__ __forceinline__ float sigm(float x) { return 1.f / (1.f + __expf(-x)); }
__device__ __forceinline__ float tanh_fast(float x) {
  x = fminf(fmaxf(x, -15.f), 15.f);
  float e2 = __expf(2.f * x);
  return (e2 - 1.f) / (e2 + 1.f);
}

// ---------- fused 2-layer MLP: Y_f32 = relu(X@W1^T+b1)@W2^T+b2, hi/lo 3-term ----------
__global__ __launch_bounds__(256, 3) void mlp_kernel(
    const float* __restrict__ X, float* __restrict__ Y,
    const float* __restrict__ W1, const float* __restrict__ B1,
    const float* __restrict__ W2, const float* __restrict__ B2, int M) {
  __shared__ __align__(16) unsigned short w1h[512 * 8], w1l[512 * 8];
  __shared__ __align__(16) unsigned short w2h[512 * 8], w2l[512 * 8];
  __shared__ __align__(16) float hbuf[4][16 * 68];  // f32 transpose buf, 2-way banks
  int tid = threadIdx.x, wid = tid >> 6, lane = tid & 63;
  int r = lane & 15, kb = lane >> 4;
  for (int idx = tid; idx < 512; idx += 256) {  // frag-order weight staging
    int f = idx >> 6, l = idx & 63;
    int nt = f >> 1, kc = f & 1;
    int n = nt * 16 + (l & 15), k0 = kc * 32 + (l >> 4) * 8;
    bf16x8 h, lo;
    split8(W1 + n * 64 + k0, &h, &lo);
    *reinterpret_cast<bf16x8*>(w1h + idx * 8) = h;
    *reinterpret_cast<bf16x8*>(w1l + idx * 8) = lo;
    split8(W2 + n * 64 + k0, &h, &lo);
    *reinterpret_cast<bf16x8*>(w2h + idx * 8) = h;
    *reinterpret_cast<bf16x8*>(w2l + idx * 8) = lo;
  }
  __syncthreads();
  float b1v[4], b2v[4];
#pragma unroll
  for (int nt = 0; nt < 4; ++nt) {
    b1v[nt] = B1[nt * 16 + r];
    b2v[nt] = B2[nt * 16 + r];
  }
  float* hl = hbuf[wid];
  int tiles = M >> 4;
  for (int t = blockIdx.x * 4 + wid; t < tiles; t += gridDim.x * 4) {
    int row0 = t << 4;
    const float* xp = X + (size_t)(row0 + r) * 64 + kb * 8;
    bf16x8 a0h, a0l, a1h, a1l;
    split8(xp, &a0h, &a0l);
    split8(xp + 32, &a1h, &a1l);
#pragma unroll
    for (int nt = 0; nt < 4; ++nt) {
      f32x4 c; c[0] = c[1] = c[2] = c[3] = b1v[nt];
      bf16x8 wh = *reinterpret_cast<const bf16x8*>(w1h + ((nt * 2 + 0) * 64 + lane) * 8);
      bf16x8 wl = *reinterpret_cast<const bf16x8*>(w1l + ((nt * 2 + 0) * 64 + lane) * 8);
      c = mfma16(a0l, wh, c); c = mfma16(a0h, wl, c); c = mfma16(a0h, wh, c);
      wh = *reinterpret_cast<const bf16x8*>(w1h + ((nt * 2 + 1) * 64 + lane) * 8);
      wl = *reinterpret_cast<const bf16x8*>(w1l + ((nt * 2 + 1) * 64 + lane) * 8);
      c = mfma16(a1l, wh, c); c = mfma16(a1h, wl, c); c = mfma16(a1h, wh, c);
#pragma unroll
      for (int i = 0; i < 4; ++i)
        hl[(kb * 4 + i) * 68 + nt * 16 + r] = fmaxf(c[i], 0.f);  // D layout -> row-major
    }
    // same-wave LDS RAW: DS pipe is in-order within a wave
    bf16x8 h0h, h0l, h1h, h1l;
    split8(hl + r * 68 + kb * 8, &h0h, &h0l);
    split8(hl + r * 68 + 32 + kb * 8, &h1h, &h1l);
    float* yp = Y + (size_t)row0 * 64;
#pragma unroll
    for (int nt = 0; nt < 4; ++nt) {
      f32x4 c; c[0] = c[1] = c[2] = c[3] = b2v[nt];
      bf16x8 wh = *reinterpret_cast<const bf16x8*>(w2h + ((nt * 2 + 0) * 64 + lane) * 8);
      bf16x8 wl = *reinterpret_cast<const bf16x8*>(w2l + ((nt * 2 + 0) * 64 + lane) * 8);
      c = mfma16(h0l, wh, c); c = mfma16(h0h, wl, c); c = mfma16(h0h, wh, c);
      wh = *reinterpret_cast<const bf16x8*>(w2h + ((nt * 2 + 1) * 64 + lane) * 8);
      wl = *reinterpret_cast<const bf16x8*>(w2l + ((nt * 2 + 1) * 64 + lane) * 8);
      c = mfma16(h1l, wh, c); c = mfma16(h1h, wl, c); c = mfma16(h1h, wh, c);
#pragma unroll
      for (int i = 0; i < 4; ++i)
        yp[(kb * 4 + i) * 64 + nt * 16 + r] = c[i];
    }
  }
}

// ---------- GRU cell, in place, hi/lo 3-term. KX=64: x=Xa. KX=128: x=[Xa|flip_pair(H)] ----------
template <int KX>
__global__ __launch_bounds__(512, 2) void gru_kernel(
    const float* __restrict__ Xa, float* __restrict__ H,
    const float* __restrict__ Wih, const float* __restrict__ Whh,
    const float* __restrict__ Bih, const float* __restrict__ Bhh, int M) {
  constexpr int NKC_X = KX / 32;
  constexpr int NFX = 12 * NKC_X;
  __shared__ __align__(16) unsigned short wihH[NFX * 64 * 8], wihL[NFX * 64 * 8];
  __shared__ __align__(16) unsigned short whhH[24 * 64 * 8], whhL[24 * 64 * 8];
  int tid = threadIdx.x;
  for (int idx = tid; idx < NFX * 64; idx += 512) {
    int f = idx >> 6, l = idx & 63;
    int nt = f / NKC_X, kc = f % NKC_X;
    int n = nt * 16 + (l & 15), k0 = kc * 32 + (l >> 4) * 8;
    bf16x8 h, lo;
    split8(Wih + n * KX + k0, &h, &lo);
    *reinterpret_cast<bf16x8*>(wihH + idx * 8) = h;
    *reinterpret_cast<bf16x8*>(wihL + idx * 8) = lo;
  }
  for (int idx = tid; idx < 24 * 64; idx += 512) {
    int f = idx >> 6, l = idx & 63;
    int nt = f >> 1, kc = f & 1;
    int n = nt * 16 + (l & 15), k0 = kc * 32 + (l >> 4) * 8;
    bf16x8 h, lo;
    split8(Whh + n * 64 + k0, &h, &lo);
    *reinterpret_cast<bf16x8*>(whhH + idx * 8) = h;
    *reinterpret_cast<bf16x8*>(whhL + idx * 8) = lo;
  }
  __syncthreads();
  int wid = tid >> 6, lane = tid & 63;
  int r = lane & 15, kb = lane >> 4;
  float bihv[12], bhhv[12];
#pragma unroll
  for (int nt = 0; nt < 12; ++nt) {
    bihv[nt] = Bih[nt * 16 + r];
    bhhv[nt] = Bhh[nt * 16 + r];
  }
  int tiles = M >> 4;
  for (int t = blockIdx.x * 8 + wid; t < tiles; t += gridDim.x * 8) {
    int row0 = t << 4;
    bf16x8 axh[NKC_X], axl[NKC_X];
#pragma unroll
    for (int kc = 0; kc < 2; ++kc)
      split8(Xa + (size_t)(row0 + r) * 64 + kc * 32 + kb * 8, &axh[kc], &axl[kc]);
    if (KX == 128) {
#pragma unroll
      for (int kc = 0; kc < 2; ++kc)  // pair-flip lives inside this 16-row tile
        split8(H + (size_t)((row0 + r) ^ 1) * 64 + kc * 32 + kb * 8, &axh[2 + kc], &axl[2 + kc]);
    }
    bf16x8 ahh[2], ahl[2];
#pragma unroll
    for (int kc = 0; kc < 2; ++kc)
      split8(H + (size_t)(row0 + r) * 64 + kc * 32 + kb * 8, &ahh[kc], &ahl[kc]);
    float hval[4][4];
#pragma unroll
    for (int nt = 0; nt < 4; ++nt)
#pragma unroll
      for (int i = 0; i < 4; ++i)
        hval[nt][i] = H[(size_t)(row0 + kb * 4 + i) * 64 + nt * 16 + r];
    float rg[4][4], zg[4][4];
#pragma unroll
    for (int nt = 0; nt < 12; ++nt) {
      f32x4 ci; ci[0] = ci[1] = ci[2] = ci[3] = bihv[nt];
#pragma unroll
      for (int kc = 0; kc < NKC_X; ++kc) {
        bf16x8 wh = *reinterpret_cast<const bf16x8*>(wihH + ((nt * NKC_X + kc) * 64 + lane) * 8);
        bf16x8 wl = *reinterpret_cast<const bf16x8*>(wihL + ((nt * NKC_X + kc) * 64 + lane) * 8);
        ci = mfma16(axl[kc], wh, ci);
        ci = mfma16(axh[kc], wl, ci);
        ci = mfma16(axh[kc], wh, ci);
      }
      f32x4 ch; ch[0] = ch[1] = ch[2] = ch[3] = bhhv[nt];
#pragma unroll
      for (int kc = 0; kc < 2; ++kc) {
        bf16x8 wh = *reinterpret_cast<const bf16x8*>(whhH + ((nt * 2 + kc) * 64 + lane) * 8);
        bf16x8 wl = *reinterpret_cast<const bf16x8*>(whhL + ((nt * 2 + kc) * 64 + lane) * 8);
        ch = mfma16(ahl[kc], wh, ch);
        ch = mfma16(ahh[kc], wl, ch);
        ch = mfma16(ahh[kc], wh, ch);
      }
      if (nt < 4) {
#pragma unroll
        for (int i = 0; i < 4; ++i) rg[nt][i] = sigm(ci[i] + ch[i]);
      } else if (nt < 8) {
#pragma unroll
        for (int i = 0; i < 4; ++i) zg[nt - 4][i] = sigm(ci[i] + ch[i]);
      } else {
        int q = nt - 8;
#pragma unroll
        for (int i = 0; i < 4; ++i) {
          float tn = tanh_fast(ci[i] + rg[q][i] * ch[i]);
          float hn = (1.f - zg[q][i]) * tn + zg[q][i] * hval[q][i];
          H[(size_t)(row0 + kb * 4 + i) * 64 + q * 16 + r] = hn;
        }
      }
    }
  }
}

// ---------- CSR gather aggregation: out[dst] = sum msg[src] (f32 messages) ----------
__global__ __launch_bounds__(256, 6) void aggr_kernel(
    const float* __restrict__ msg, const int* __restrict__ rowptr,
    const int* __restrict__ srcv, float* __restrict__ out, int Ndst) {
  int gtid = blockIdx.x * 256 + threadIdx.x;
  int w = gtid >> 6, lane = gtid & 63;
  int nw = gridDim.x * 4;
  for (int dst = w; dst < Ndst; dst += nw) {
    int p0 = rowptr[dst], p1 = rowptr[dst + 1];
    float acc = 0.f;
    int j = p0;
    for (; j + 4 <= p1; j += 4) {
      int s0 = srcv[j], s1 = srcv[j + 1], s2 = srcv[j + 2], s3 = srcv[j + 3];
      acc += msg[(size_t)s0 * 64 + lane];
      acc += msg[(size_t)s1 * 64 + lane];
      acc += msg[(size_t)s2 * 64 + lane];
      acc += msg[(size_t)s3 * 64 + lane];
    }
    for (; j < p1; ++j) acc += msg[(size_t)srcv[j] * 64 + lane];
    out[(size_t)dst * 64 + lane] = acc;
  }
}

// ---------- CSR build ----------
__global__ void count_kernel(const int* __restrict__ le, const int* __restrict__ ce,
                             int* __restrict__ degL, int* __restrict__ degC, int E) {
  for (int e = blockIdx.x * 256 + threadIdx.x; e < E; e += gridDim.x * 256) {
    atomicAdd(&degL[le[e]], 1);
    atomicAdd(&degC[ce[e]], 1);
  }
}
__global__ void scan_pass1(const int* __restrict__ in, int* __restrict__ bsum, int N, int chunk) {
  int b = blockIdx.x, t = threadIdx.x;
  int base = b * chunk;
  int seg = (chunk + 255) >> 8;
  int a = base + t * seg;
  int e = min(min(N, base + chunk), a + seg);
  int s = 0;
  for (int i = a; i < e; ++i) s += in[i];
  __shared__ int red[256];
  red[t] = s; __syncthreads();
  for (int off = 128; off > 0; off >>= 1) {
    if (t < off) red[t] += red[t + off];
    __syncthreads();
  }
  if (t == 0) bsum[b] = red[0];
}
__global__ void scan_pass2(int* bsum, int* totalOut) {
  __shared__ int sc[256];
  int t = threadIdx.x;
  int v = bsum[t];
  sc[t] = v; __syncthreads();
  for (int off = 1; off < 256; off <<= 1) {
    int u = (t >= off) ? sc[t - off] : 0;
    __syncthreads();
    sc[t] += u;
    __syncthreads();
  }
  bsum[t] = sc[t] - v;
  if (t == 255) *totalOut = sc[255];
}
__global__ void scan_pass3(const int* __restrict__ in, const int* __restrict__ bsum,
                           int* __restrict__ outp, int N, int chunk) {
  int b = blockIdx.x, t = threadIdx.x;
  int base = b * chunk;
  int seg = (chunk + 255) >> 8;
  int a = base + t * seg;
  int e = min(min(N, base + chunk), a + seg);
  int s = 0;
  for (int i = a; i < e; ++i) s += in[i];
  __shared__ int sc[256];
  int v = s;
  sc[t] = v; __syncthreads();
  for (int off = 1; off < 256; off <<= 1) {
    int u = (t >= off) ? sc[t - off] : 0;
    __syncthreads();
    sc[t] += u;
    __syncthreads();
  }
  int run = bsum[b] + sc[t] - v;
  for (int i = a; i < e; ++i) { outp[i] = run; run += in[i]; }
}
__global__ void fill_kernel(const int* __restrict__ le, const int* __restrict__ ce,
                            int* __restrict__ curL, int* __restrict__ curC,
                            int* __restrict__ srcL2C, int* __restrict__ srcC2L, int E) {
  for (int e = blockIdx.x * 256 + threadIdx.x; e < E; e += gridDim.x * 256) {
    int ls = le[e], cd = ce[e];
    int s1 = atomicAdd(&curC[cd], 1);
    srcL2C[s1] = ls;
    int s2 = atomicAdd(&curL[ls], 1);
    srcC2L[s2] = cd;
  }
}

// ---------- init / readout ----------
__global__ void init_emb(float* __restrict__ emb, const float* __restrict__ ini, int n) {
  for (int i = blockIdx.x * 256 + threadIdx.x; i < n; i += gridDim.x * 256)
    emb[i] = ini[i & 63];
}
__global__ void readout_sum(const float* __restrict__ lemb, const int* __restrict__ lb,
                            float* __restrict__ gsum, float* __restrict__ gcnt, int L) {
  int gtid = blockIdx.x * 256 + threadIdx.x;
  int w = gtid >> 6, lane = gtid & 63;
  int nw = gridDim.x * 4;
  int chunk = (L + nw - 1) / nw;
  int s = w * chunk, e = min(L, s + chunk);
  if (s >= e) return;
  float acc = 0.f, cnt = 0.f;
  int curb = lb[s];
  for (int row = s; row < e; ++row) {
    int b = lb[row];
    if (b != curb) {
      atomicAdd(&gsum[curb * 64 + lane], acc);
      if (lane == 0) atomicAdd(&gcnt[curb], cnt);
      acc = 0.f; cnt = 0.f; curb = b;
    }
    acc += lemb[(size_t)row * 64 + lane];
    cnt += 1.f;
  }
  atomicAdd(&gsum[curb * 64 + lane], acc);
  if (lane == 0) atomicAdd(&gcnt[curb], cnt);
}
__global__ void final_kernel(const float* __restrict__ gsum, const float* __restrict__ gcnt,
                             const float* __restrict__ W1, const float* __restrict__ B1,
                             const float* __restrict__ W2, const float* __restrict__ B2,
                             float* __restrict__ outp) {
  __shared__ float w1s[4096];
  __shared__ float w2s[64];
  int t = threadIdx.x;  // 128 threads: one per graph
  for (int i = t; i < 4096; i += 128) w1s[i] = W1[i];
  if (t < 64) w2s[t] = W2[t];
  __syncthreads();
  float x[64];
  float c = fmaxf(gcnt[t], 1.f);
#pragma unroll
  for (int d = 0; d < 64; ++d) x[d] = gsum[t * 64 + d] / c;
  float acc = B2[0];
  for (int j = 0; j < 64; ++j) {
    float h = B1[j];
#pragma unroll
    for (int k = 0; k < 64; ++k) h += x[k] * w1s[j * 64 + k];
    acc += fmaxf(h, 0.f) * w2s[j];
  }
  outp[t] = 1.f / (1.f + __expf(-acc));
}

// ---------- launch ----------
extern "C" void kernel_launch(void* const* d_in, const int* in_sizes, int n_in,
                              void* d_out, int out_size, void* d_ws, size_t ws_size,
                              hipStream_t stream) {
  const int* le = (const int*)d_in[2];
  const int* ce = (const int*)d_in[3];
  const int* lb = (const int*)d_in[4];
  const float* l_init = (const float*)d_in[5];
  const float* c_init = (const float*)d_in[6];
  const float* l2c_W1 = (const float*)d_in[7];
  const float* l2c_b1 = (const float*)d_in[8];
  const float* l2c_W2 = (const float*)d_in[9];
  const float* l2c_b2 = (const float*)d_in[10];
  const float* c2l_W1 = (const float*)d_in[11];
  const float* c2l_b1 = (const float*)d_in[12];
  const float* c2l_W2 = (const float*)d_in[13];
  const float* c2l_b2 = (const float*)d_in[14];
  const float* gc_Wih = (const float*)d_in[15];
  const float* gc_Whh = (const float*)d_in[16];
  const float* gc_bih = (const float*)d_in[17];
  const float* gc_bhh = (const float*)d_in[18];
  const float* gl_Wih = (const float*)d_in[19];
  const float* gl_Whh = (const float*)d_in[20];
  const float* gl_bih = (const float*)d_in[21];
  const float* gl_bhh = (const float*)d_in[22];
  const float* ro_W1 = (const float*)d_in[23];
  const float* ro_b1 = (const float*)d_in[24];
  const float* ro_W2 = (const float*)d_in[25];
  const float* ro_b2 = (const float*)d_in[26];
  const int E = in_sizes[2];
  const int L = in_sizes[4];
  const int C = 100000;

  char* p = (char*)d_ws;
  auto alloc = [&](size_t b) -> char* {
    char* r = p;
    p += (b + 255) & ~(size_t)255;
    return r;
  };
  float* l_emb = (float*)alloc((size_t)L * 64 * 4);
  float* c_emb = (float*)alloc((size_t)C * 64 * 4);
  float* l_msg = (float*)alloc((size_t)L * 64 * 4);
  float* c_msg = (float*)alloc((size_t)C * 64 * 4);
  float* l2c_aggr = (float*)alloc((size_t)C * 64 * 4);
  float* c2l_aggr = (float*)alloc((size_t)L * 64 * 4);
  int* rowptrC = (int*)alloc((size_t)(C + 1) * 4);
  int* rowptrL = (int*)alloc((size_t)(L + 1) * 4);
  int* curC = (int*)alloc((size_t)C * 4);
  int* curL = (int*)alloc((size_t)L * 4);
  int* srcL2C = (int*)alloc((size_t)E * 4);
  int* srcC2L = (int*)alloc((size_t)E * 4);
  int* bsum = (int*)alloc(256 * 4);
  float* gsum = (float*)alloc(128 * 64 * 4);
  float* gcnt = (float*)alloc(128 * 4);

  // CSR build (once per launch; reused by all 16 aggregations)
  hipMemsetAsync(curC, 0, (size_t)C * 4, stream);
  hipMemsetAsync(curL, 0, (size_t)L * 4, stream);
  count_kernel<<<512, 256, 0, stream>>>(le, ce, curL, curC, E);
  int chC = (C + 255) / 256, chL = (L + 255) / 256;
  scan_pass1<<<256, 256, 0, stream>>>(curC, bsum, C, chC);
  scan_pass2<<<1, 256, 0, stream>>>(bsum, rowptrC + C);
  scan_pass3<<<256, 256, 0, stream>>>(curC, bsum, rowptrC, C, chC);
  scan_pass1<<<256, 256, 0, stream>>>(curL, bsum, L, chL);
  scan_pass2<<<1, 256, 0, stream>>>(bsum, rowptrL + L);
  scan_pass3<<<256, 256, 0, stream>>>(curL, bsum, rowptrL, L, chL);
  hipMemcpyAsync(curC, rowptrC, (size_t)C * 4, hipMemcpyDeviceToDevice, stream);
  hipMemcpyAsync(curL, rowptrL, (size_t)L * 4, hipMemcpyDeviceToDevice, stream);
  fill_kernel<<<512, 256, 0, stream>>>(le, ce, curL, curC, srcL2C, srcC2L, E);

  init_emb<<<1024, 256, 0, stream>>>(l_emb, l_init, L * 64);
  init_emb<<<1024, 256, 0, stream>>>(c_emb, c_init, C * 64);

  for (int it = 0; it < 8; ++it) {
    mlp_kernel<<<768, 256, 0, stream>>>(l_emb, l_msg, l2c_W1, l2c_b1, l2c_W2, l2c_b2, L);
    aggr_kernel<<<2048, 256, 0, stream>>>(l_msg, rowptrC, srcL2C, l2c_aggr, C);
    mlp_kernel<<<768, 256, 0, stream>>>(c_emb, c_msg, c2l_W1, c2l_b1, c2l_W2, c2l_b2, C);
    aggr_kernel<<<2048, 256, 0, stream>>>(c_msg, rowptrL, srcC2L, c2l_aggr, L);
    gru_kernel<64><<<256, 512, 0, stream>>>(l2c_aggr, c_emb, gc_Wih, gc_Whh, gc_bih, gc_bhh, C);
    gru_kernel<128><<<256, 512, 0, stream>>>(c2l_aggr, l_emb, gl_Wih, gl_Whh, gl_bih, gl_bhh, L);
  }

  hipMemsetAsync(gsum, 0, 128 * 64 * 4, stream);
  hipMemsetAsync(gcnt, 0, 128 * 4, stream);
  readout_sum<<<512, 256, 0, stream>>>(l_emb, lb, gsum, gcnt, L);
  final_kernel<<<1, 128, 0, stream>>>(gsum, gcnt, ro_W1, ro_b1, ro_W2, ro_b2,
                                      (float*)d_out);
}